// Round 3
// baseline (150.602 us; speedup 1.0000x reference)
//
#include <hip/hip_runtime.h>
#include <hip/hip_bf16.h>

#define NMAX 2048
#define HH 128
#define WW 128
#define NSEG 8
#define SEG 256            // NMAX / NSEG
#define NEARP 0.1f

// Runtime-adaptive input load: reference ships fp32; guard against a bf16
// dataset variant. Detected from intrinsics[0] (==150.0 iff fp32; bf16-packed
// bytes read as float give a denormal ~2e-41).
static __device__ __forceinline__ float ldin(const void* p, int i, bool is32) {
    return is32 ? ((const float*)p)[i]
                : __bfloat162float(((const __hip_bfloat16*)p)[i]);
}
static __device__ __forceinline__ bool detect32(const void* intr) {
    return ((const float*)intr)[0] > 1.0f;
}
static __device__ __forceinline__ void stout(void* out, int i, float v, bool is32) {
    if (is32) ((float*)out)[i] = v;
    else      ((__hip_bfloat16*)out)[i] = __float2bfloat16(v);
}

// ---------------------------------------------------------------- preprocess
__global__ __launch_bounds__(256) void gs_preprocess(
    const void* __restrict__ means,
    const void* __restrict__ log_scales,
    const void* __restrict__ rots,
    const void* __restrict__ colors,
    const void* __restrict__ opac,
    const void* __restrict__ intr,
    const void* __restrict__ c2w,
    int n,
    unsigned long long* __restrict__ keys,
    float* __restrict__ params)
{
    int i = blockIdx.x * blockDim.x + threadIdx.x;
    if (i >= NMAX) return;
    bool is32 = detect32(intr);
    if (i >= n) { keys[i] = 0xFFFFFFFFFFFFFFFFull; return; }

    // camera: Rwc = Rcw^T, twc = -Rwc @ tcw
    float Rwc[3][3], twc[3];
    {
        float Rcw[3][3], tcw[3];
        for (int r = 0; r < 3; ++r) {
            for (int c = 0; c < 3; ++c) Rcw[r][c] = ldin(c2w, r * 4 + c, is32);
            tcw[r] = ldin(c2w, r * 4 + 3, is32);
        }
        for (int r = 0; r < 3; ++r)
            for (int c = 0; c < 3; ++c) Rwc[r][c] = Rcw[c][r];
        for (int r = 0; r < 3; ++r)
            twc[r] = -(Rwc[r][0] * tcw[0] + Rwc[r][1] * tcw[1] + Rwc[r][2] * tcw[2]);
    }
    float fx = ldin(intr, 0, is32), fy = ldin(intr, 4, is32);
    float cx = ldin(intr, 2, is32), cy = ldin(intr, 5, is32);

    float mx = ldin(means, 3 * i, is32), my = ldin(means, 3 * i + 1, is32),
          mz = ldin(means, 3 * i + 2, is32);
    float px = Rwc[0][0] * mx + Rwc[0][1] * my + Rwc[0][2] * mz + twc[0];
    float py = Rwc[1][0] * mx + Rwc[1][1] * my + Rwc[1][2] * mz + twc[1];
    float pz = Rwc[2][0] * mx + Rwc[2][1] * my + Rwc[2][2] * mz + twc[2];
    bool valid = pz > NEARP;
    float zc = fmaxf(pz, NEARP);
    float izc = 1.0f / zc;
    float u = fx * px * izc + cx;
    float v = fy * py * izc + cy;

    // quaternion -> R
    float qw = ldin(rots, 4 * i, is32), qx = ldin(rots, 4 * i + 1, is32),
          qy = ldin(rots, 4 * i + 2, is32), qz = ldin(rots, 4 * i + 3, is32);
    float nrm = sqrtf(qw * qw + qx * qx + qy * qy + qz * qz);
    float inv = 1.0f / fmaxf(nrm, 1e-8f);
    qw *= inv; qx *= inv; qy *= inv; qz *= inv;
    float xx = qx * qx, yy = qy * qy, zz = qz * qz;
    float xy = qx * qy, xz = qx * qz, yz = qy * qz;
    float wx = qw * qx, wy = qw * qy, wz = qw * qz;
    float R[3][3] = {
        {1.f - 2.f * (yy + zz), 2.f * (xy - wz),       2.f * (xz + wy)},
        {2.f * (xy + wz),       1.f - 2.f * (xx + zz), 2.f * (yz - wx)},
        {2.f * (xz - wy),       2.f * (yz + wx),       1.f - 2.f * (xx + yy)}
    };
    float s2[3];
    for (int k = 0; k < 3; ++k) s2[k] = __expf(2.0f * ldin(log_scales, 3 * i + k, is32));

    // cov3d = R diag(s2) R^T + 1e-6 I
    float M[3][3];
    for (int r = 0; r < 3; ++r)
        for (int c = 0; c < 3; ++c)
            M[r][c] = R[r][0] * s2[0] * R[c][0] + R[r][1] * s2[1] * R[c][1]
                    + R[r][2] * s2[2] * R[c][2];
    M[0][0] += 1e-6f; M[1][1] += 1e-6f; M[2][2] += 1e-6f;

    // cov_cam = Rwc M Rwc^T
    float TM[3][3];
    for (int r = 0; r < 3; ++r)
        for (int c = 0; c < 3; ++c)
            TM[r][c] = Rwc[r][0] * M[0][c] + Rwc[r][1] * M[1][c] + Rwc[r][2] * M[2][c];
    float CC[3][3];
    for (int r = 0; r < 3; ++r)
        for (int c = 0; c < 3; ++c)
            CC[r][c] = TM[r][0] * Rwc[c][0] + TM[r][1] * Rwc[c][1] + TM[r][2] * Rwc[c][2];

    // J rows
    float J0[3] = {fx * izc, 0.0f, -fx * px * izc * izc};
    float J1[3] = {0.0f, fy * izc, -fy * py * izc * izc};
    float t0[3], t1[3];
    for (int c = 0; c < 3; ++c) {
        t0[c] = J0[0] * CC[0][c] + J0[1] * CC[1][c] + J0[2] * CC[2][c];
        t1[c] = J1[0] * CC[0][c] + J1[1] * CC[1][c] + J1[2] * CC[2][c];
    }
    float a  = t0[0] * J0[0] + t0[1] * J0[1] + t0[2] * J0[2] + 0.3f;
    float bq = t0[0] * J1[0] + t0[1] * J1[1] + t0[2] * J1[2];
    float cq = t1[0] * J1[0] + t1[1] * J1[1] + t1[2] * J1[2] + 0.3f;
    float det = fmaxf(a * cq - bq * bq, 1e-12f);
    float idet = 1.0f / det;
    float cA = cq * idet, cB = -bq * idet, cCc = a * idet;

    float o  = ldin(opac, i, is32);
    float op = valid ? (1.0f / (1.0f + __expf(-o))) : 0.0f;
    float cr = fminf(fmaxf(ldin(colors, 3 * i, is32), 0.f), 1.f);
    float cg = fminf(fmaxf(ldin(colors, 3 * i + 1, is32), 0.f), 1.f);
    float cb = fminf(fmaxf(ldin(colors, 3 * i + 2, is32), 0.f), 1.f);

    float zkey = valid ? zc : __builtin_inff();
    keys[i] = (((unsigned long long)__float_as_uint(zkey)) << 32) | (unsigned int)i;

    float* p = params + i * 12;
    p[0] = u;  p[1] = v;  p[2] = cA; p[3] = cB; p[4] = cCc; p[5] = op;
    p[6] = cr; p[7] = cg; p[8] = cb; p[9] = 0.f; p[10] = 0.f; p[11] = 0.f;
}

// -------------------------- bitonic sort (stable via index-in-key) + gather
__global__ __launch_bounds__(256) void gs_sort_gather(
    const unsigned long long* __restrict__ keys_in,
    const float* __restrict__ params_in,
    float* __restrict__ params_sorted,
    int n)
{
    __shared__ unsigned long long sk[NMAX];
    int t = threadIdx.x;
    #pragma unroll
    for (int e = 0; e < 8; ++e) sk[t + e * 256] = keys_in[t + e * 256];
    __syncthreads();
    for (int size = 2; size <= NMAX; size <<= 1) {
        for (int stride = size >> 1; stride > 0; stride >>= 1) {
            #pragma unroll
            for (int e = 0; e < 8; ++e) {
                int i = t + e * 256;
                int j = i ^ stride;
                if (j > i) {
                    bool asc = ((i & size) == 0);
                    unsigned long long ka = sk[i], kb = sk[j];
                    if ((ka > kb) == asc) { sk[i] = kb; sk[j] = ka; }
                }
            }
            __syncthreads();
        }
    }
    #pragma unroll
    for (int e = 0; e < 8; ++e) {
        int g = t + e * 256;
        unsigned int src = (unsigned int)(sk[g] & 0xffffffffull);
        float* dst = params_sorted + g * 12;
        if (src < (unsigned int)n) {
            const float* s = params_in + src * 12;
            #pragma unroll
            for (int k = 0; k < 12; ++k) dst[k] = s[k];
        } else {
            #pragma unroll
            for (int k = 0; k < 12; ++k) dst[k] = 0.f;
        }
    }
}

// ---------------------------------------------------------------- render (segmented)
__global__ __launch_bounds__(256) void gs_render(
    const float* __restrict__ params_sorted,
    float4* __restrict__ segbuf)
{
    __shared__ float sp[SEG * 12];
    int seg = blockIdx.y;
    int t = threadIdx.x;

    const float4* src = (const float4*)(params_sorted + seg * SEG * 12);
    float4* dst = (float4*)sp;
    #pragma unroll
    for (int k = t; k < SEG * 3; k += 256) dst[k] = src[k];
    __syncthreads();

    int pid = blockIdx.x * 256 + t;
    float pxf = (float)(pid & (WW - 1));
    float pyf = (float)(pid >> 7);

    float T = 1.0f, r = 0.f, g = 0.f, b = 0.f;
    for (int i = 0; i < SEG; ++i) {
        const float* gp = sp + i * 12;
        float dx = pxf - gp[0];
        float dy = pyf - gp[1];
        float pwr = -0.5f * (gp[2] * dx * dx + gp[4] * dy * dy) - gp[3] * dx * dy;
        pwr = fminf(pwr, 0.0f);
        float alpha = fminf(fmaxf(gp[5] * __expf(pwr), 0.0f), 0.99f);
        float wgt = alpha * T;
        r = fmaf(wgt, gp[6], r);
        g = fmaf(wgt, gp[7], g);
        b = fmaf(wgt, gp[8], b);
        T *= (1.0f - alpha);
    }
    segbuf[seg * (HH * WW) + pid] = make_float4(r, g, b, T);
}

// ---------------------------------------------------------------- combine
__global__ __launch_bounds__(256) void gs_combine(
    const float4* __restrict__ segbuf,
    void* __restrict__ out,
    const void* __restrict__ intr)
{
    int pid = blockIdx.x * 256 + threadIdx.x;
    if (pid >= HH * WW) return;
    bool is32 = detect32(intr);
    float r = 0.f, g = 0.f, b = 0.f, T = 1.0f;
    #pragma unroll
    for (int s = 0; s < NSEG; ++s) {
        float4 vv = segbuf[s * (HH * WW) + pid];
        r = fmaf(T, vv.x, r);
        g = fmaf(T, vv.y, g);
        b = fmaf(T, vv.z, b);
        T *= vv.w;
    }
    stout(out, pid * 3 + 0, r, is32);
    stout(out, pid * 3 + 1, g, is32);
    stout(out, pid * 3 + 2, b, is32);
}

// -------------------------------- fallback: fused render over all gaussians
// (used only if ws_size can't hold the 2 MB segment buffer)
__global__ __launch_bounds__(256) void gs_render_all(
    const float* __restrict__ params_sorted,
    void* __restrict__ out,
    const void* __restrict__ intr)
{
    __shared__ float sp[SEG * 12];
    int t = threadIdx.x;
    int pid = blockIdx.x * 256 + t;
    bool is32 = detect32(intr);
    float pxf = (float)(pid & (WW - 1));
    float pyf = (float)(pid >> 7);

    float T = 1.0f, r = 0.f, g = 0.f, b = 0.f;
    for (int seg = 0; seg < NSEG; ++seg) {
        __syncthreads();
        const float4* src = (const float4*)(params_sorted + seg * SEG * 12);
        float4* dst = (float4*)sp;
        #pragma unroll
        for (int k = t; k < SEG * 3; k += 256) dst[k] = src[k];
        __syncthreads();
        for (int i = 0; i < SEG; ++i) {
            const float* gp = sp + i * 12;
            float dx = pxf - gp[0];
            float dy = pyf - gp[1];
            float pwr = -0.5f * (gp[2] * dx * dx + gp[4] * dy * dy) - gp[3] * dx * dy;
            pwr = fminf(pwr, 0.0f);
            float alpha = fminf(fmaxf(gp[5] * __expf(pwr), 0.0f), 0.99f);
            float wgt = alpha * T;
            r = fmaf(wgt, gp[6], r);
            g = fmaf(wgt, gp[7], g);
            b = fmaf(wgt, gp[8], b);
            T *= (1.0f - alpha);
        }
    }
    stout(out, pid * 3 + 0, r, is32);
    stout(out, pid * 3 + 1, g, is32);
    stout(out, pid * 3 + 2, b, is32);
}

extern "C" void kernel_launch(void* const* d_in, const int* in_sizes, int n_in,
                              void* d_out, int out_size, void* d_ws, size_t ws_size,
                              hipStream_t stream)
{
    const void* means      = d_in[0];
    const void* log_scales = d_in[1];
    const void* rotations  = d_in[2];
    const void* colors     = d_in[3];
    const void* opacities  = d_in[4];
    const void* intrinsics = d_in[5];
    const void* cam2world  = d_in[6];

    int n = in_sizes[4];
    if (n > NMAX) n = NMAX;

    // workspace layout
    size_t off_keys   = 0;                       // 16 KB
    size_t off_params = NMAX * 8;                // 96 KB
    size_t off_sorted = off_params + NMAX * 48;  // 96 KB
    size_t off_seg    = off_sorted + NMAX * 48;  // 2 MB
    size_t need_seg   = off_seg + (size_t)NSEG * HH * WW * 16;

    unsigned long long* keys = (unsigned long long*)((char*)d_ws + off_keys);
    float* params  = (float*)((char*)d_ws + off_params);
    float* sortedp = (float*)((char*)d_ws + off_sorted);
    float4* segbuf = (float4*)((char*)d_ws + off_seg);

    gs_preprocess<<<NMAX / 256, 256, 0, stream>>>(
        means, log_scales, rotations, colors, opacities, intrinsics, cam2world,
        n, keys, params);
    gs_sort_gather<<<1, 256, 0, stream>>>(keys, params, sortedp, n);

    if (ws_size >= need_seg) {
        dim3 rg(HH * WW / 256, NSEG);
        gs_render<<<rg, 256, 0, stream>>>(sortedp, segbuf);
        gs_combine<<<HH * WW / 256, 256, 0, stream>>>(segbuf, d_out, intrinsics);
    } else {
        gs_render_all<<<HH * WW / 256, 256, 0, stream>>>(sortedp, d_out, intrinsics);
    }
}

// Round 4
// 128.726 us; speedup vs baseline: 1.1699x; 1.1699x over previous
//
#include <hip/hip_runtime.h>
#include <hip/hip_bf16.h>

#define NMAX 2048
#define HH 128
#define WW 128
#define NSEG 8
#define SEG 256            // NMAX / NSEG
#define NEARP 0.1f

// Runtime-adaptive input load: reference ships fp32; guard against a bf16
// dataset variant. Detected from intrinsics[0] (==150.0 iff fp32; bf16-packed
// bytes read as float give a denormal ~2e-41).
static __device__ __forceinline__ float ldin(const void* p, int i, bool is32) {
    return is32 ? ((const float*)p)[i]
                : __bfloat162float(((const __hip_bfloat16*)p)[i]);
}
static __device__ __forceinline__ bool detect32(const void* intr) {
    return ((const float*)intr)[0] > 1.0f;
}
static __device__ __forceinline__ void stout(void* out, int i, float v, bool is32) {
    if (is32) ((float*)out)[i] = v;
    else      ((__hip_bfloat16*)out)[i] = __float2bfloat16(v);
}

// ---------------------------------------------------------------- preprocess
__global__ __launch_bounds__(256) void gs_preprocess(
    const void* __restrict__ means,
    const void* __restrict__ log_scales,
    const void* __restrict__ rots,
    const void* __restrict__ colors,
    const void* __restrict__ opac,
    const void* __restrict__ intr,
    const void* __restrict__ c2w,
    int n,
    unsigned long long* __restrict__ keys,
    float* __restrict__ params)
{
    int i = blockIdx.x * blockDim.x + threadIdx.x;
    if (i >= NMAX) return;
    bool is32 = detect32(intr);
    if (i >= n) {
        // unique key (sorts to the end, stable by index); record zeroed at scatter
        keys[i] = (((unsigned long long)0x7f800000u) << 32) | (unsigned int)i;
        return;
    }

    // camera: Rwc = Rcw^T, twc = -Rwc @ tcw
    float Rwc[3][3], twc[3];
    {
        float Rcw[3][3], tcw[3];
        for (int r = 0; r < 3; ++r) {
            for (int c = 0; c < 3; ++c) Rcw[r][c] = ldin(c2w, r * 4 + c, is32);
            tcw[r] = ldin(c2w, r * 4 + 3, is32);
        }
        for (int r = 0; r < 3; ++r)
            for (int c = 0; c < 3; ++c) Rwc[r][c] = Rcw[c][r];
        for (int r = 0; r < 3; ++r)
            twc[r] = -(Rwc[r][0] * tcw[0] + Rwc[r][1] * tcw[1] + Rwc[r][2] * tcw[2]);
    }
    float fx = ldin(intr, 0, is32), fy = ldin(intr, 4, is32);
    float cx = ldin(intr, 2, is32), cy = ldin(intr, 5, is32);

    float mx = ldin(means, 3 * i, is32), my = ldin(means, 3 * i + 1, is32),
          mz = ldin(means, 3 * i + 2, is32);
    float px = Rwc[0][0] * mx + Rwc[0][1] * my + Rwc[0][2] * mz + twc[0];
    float py = Rwc[1][0] * mx + Rwc[1][1] * my + Rwc[1][2] * mz + twc[1];
    float pz = Rwc[2][0] * mx + Rwc[2][1] * my + Rwc[2][2] * mz + twc[2];
    bool valid = pz > NEARP;
    float zc = fmaxf(pz, NEARP);
    float izc = 1.0f / zc;
    float u = fx * px * izc + cx;
    float v = fy * py * izc + cy;

    // quaternion -> R
    float qw = ldin(rots, 4 * i, is32), qx = ldin(rots, 4 * i + 1, is32),
          qy = ldin(rots, 4 * i + 2, is32), qz = ldin(rots, 4 * i + 3, is32);
    float nrm = sqrtf(qw * qw + qx * qx + qy * qy + qz * qz);
    float inv = 1.0f / fmaxf(nrm, 1e-8f);
    qw *= inv; qx *= inv; qy *= inv; qz *= inv;
    float xx = qx * qx, yy = qy * qy, zz = qz * qz;
    float xy = qx * qy, xz = qx * qz, yz = qy * qz;
    float wx = qw * qx, wy = qw * qy, wz = qw * qz;
    float R[3][3] = {
        {1.f - 2.f * (yy + zz), 2.f * (xy - wz),       2.f * (xz + wy)},
        {2.f * (xy + wz),       1.f - 2.f * (xx + zz), 2.f * (yz - wx)},
        {2.f * (xz - wy),       2.f * (yz + wx),       1.f - 2.f * (xx + yy)}
    };
    float s2[3];
    for (int k = 0; k < 3; ++k) s2[k] = __expf(2.0f * ldin(log_scales, 3 * i + k, is32));

    // cov3d = R diag(s2) R^T + 1e-6 I
    float M[3][3];
    for (int r = 0; r < 3; ++r)
        for (int c = 0; c < 3; ++c)
            M[r][c] = R[r][0] * s2[0] * R[c][0] + R[r][1] * s2[1] * R[c][1]
                    + R[r][2] * s2[2] * R[c][2];
    M[0][0] += 1e-6f; M[1][1] += 1e-6f; M[2][2] += 1e-6f;

    // cov_cam = Rwc M Rwc^T
    float TM[3][3];
    for (int r = 0; r < 3; ++r)
        for (int c = 0; c < 3; ++c)
            TM[r][c] = Rwc[r][0] * M[0][c] + Rwc[r][1] * M[1][c] + Rwc[r][2] * M[2][c];
    float CC[3][3];
    for (int r = 0; r < 3; ++r)
        for (int c = 0; c < 3; ++c)
            CC[r][c] = TM[r][0] * Rwc[c][0] + TM[r][1] * Rwc[c][1] + TM[r][2] * Rwc[c][2];

    // J rows
    float J0[3] = {fx * izc, 0.0f, -fx * px * izc * izc};
    float J1[3] = {0.0f, fy * izc, -fy * py * izc * izc};
    float t0[3], t1[3];
    for (int c = 0; c < 3; ++c) {
        t0[c] = J0[0] * CC[0][c] + J0[1] * CC[1][c] + J0[2] * CC[2][c];
        t1[c] = J1[0] * CC[0][c] + J1[1] * CC[1][c] + J1[2] * CC[2][c];
    }
    float a  = t0[0] * J0[0] + t0[1] * J0[1] + t0[2] * J0[2] + 0.3f;
    float bq = t0[0] * J1[0] + t0[1] * J1[1] + t0[2] * J1[2];
    float cq = t1[0] * J1[0] + t1[1] * J1[1] + t1[2] * J1[2] + 0.3f;
    float det = fmaxf(a * cq - bq * bq, 1e-12f);
    float idet = 1.0f / det;
    float cA = cq * idet, cB = -bq * idet, cCc = a * idet;

    float o  = ldin(opac, i, is32);
    float op = valid ? (1.0f / (1.0f + __expf(-o))) : 0.0f;
    float cr = fminf(fmaxf(ldin(colors, 3 * i, is32), 0.f), 1.f);
    float cg = fminf(fmaxf(ldin(colors, 3 * i + 1, is32), 0.f), 1.f);
    float cb = fminf(fmaxf(ldin(colors, 3 * i + 2, is32), 0.f), 1.f);

    float zkey = valid ? zc : __builtin_inff();
    keys[i] = (((unsigned long long)__float_as_uint(zkey)) << 32) | (unsigned int)i;

    float* p = params + i * 12;
    p[0] = u;  p[1] = v;  p[2] = cA; p[3] = cB; p[4] = cCc; p[5] = op;
    p[6] = cr; p[7] = cg; p[8] = cb; p[9] = 0.f; p[10] = 0.f; p[11] = 0.f;
}

// ------------------------------- rank-by-count (stable, unique keys) + scatter
// Keys are unique ((depth_bits<<32)|index), so rank(g) = #{j : key[j] < key[g]}
// reproduces jnp.argsort's stable order exactly. One barrier; broadcast LDS scan.
__global__ __launch_bounds__(256) void gs_rank_scatter(
    const unsigned long long* __restrict__ keys_in,
    const float* __restrict__ params_in,
    float* __restrict__ params_sorted,
    int n)
{
    __shared__ unsigned long long sk[NMAX];
    int t = threadIdx.x;
    #pragma unroll
    for (int e = 0; e < 8; ++e) sk[t + e * 256] = keys_in[t + e * 256];
    __syncthreads();

    int g = blockIdx.x * 256 + t;
    unsigned long long mykey = sk[g];
    int rank = 0;
    #pragma unroll 8
    for (int j = 0; j < NMAX; ++j)
        rank += (sk[j] < mykey) ? 1 : 0;

    float* dst = params_sorted + rank * 12;
    if (g < n) {
        const float* s = params_in + g * 12;
        #pragma unroll
        for (int k = 0; k < 12; ++k) dst[k] = s[k];
    } else {
        #pragma unroll
        for (int k = 0; k < 12; ++k) dst[k] = 0.f;
    }
}

// ---------------------------------------------------------------- render (segmented)
__global__ __launch_bounds__(256) void gs_render(
    const float* __restrict__ params_sorted,
    float4* __restrict__ segbuf)
{
    __shared__ float sp[SEG * 12];
    int seg = blockIdx.y;
    int t = threadIdx.x;

    const float4* src = (const float4*)(params_sorted + seg * SEG * 12);
    float4* dst = (float4*)sp;
    #pragma unroll
    for (int k = t; k < SEG * 3; k += 256) dst[k] = src[k];
    __syncthreads();

    int pid = blockIdx.x * 256 + t;
    float pxf = (float)(pid & (WW - 1));
    float pyf = (float)(pid >> 7);

    float T = 1.0f, r = 0.f, g = 0.f, b = 0.f;
    for (int i = 0; i < SEG; ++i) {
        const float* gp = sp + i * 12;
        float dx = pxf - gp[0];
        float dy = pyf - gp[1];
        float pwr = -0.5f * (gp[2] * dx * dx + gp[4] * dy * dy) - gp[3] * dx * dy;
        pwr = fminf(pwr, 0.0f);
        float alpha = fminf(fmaxf(gp[5] * __expf(pwr), 0.0f), 0.99f);
        float wgt = alpha * T;
        r = fmaf(wgt, gp[6], r);
        g = fmaf(wgt, gp[7], g);
        b = fmaf(wgt, gp[8], b);
        T *= (1.0f - alpha);
    }
    segbuf[seg * (HH * WW) + pid] = make_float4(r, g, b, T);
}

// ---------------------------------------------------------------- combine
__global__ __launch_bounds__(256) void gs_combine(
    const float4* __restrict__ segbuf,
    void* __restrict__ out,
    const void* __restrict__ intr)
{
    int pid = blockIdx.x * 256 + threadIdx.x;
    if (pid >= HH * WW) return;
    bool is32 = detect32(intr);
    float r = 0.f, g = 0.f, b = 0.f, T = 1.0f;
    #pragma unroll
    for (int s = 0; s < NSEG; ++s) {
        float4 vv = segbuf[s * (HH * WW) + pid];
        r = fmaf(T, vv.x, r);
        g = fmaf(T, vv.y, g);
        b = fmaf(T, vv.z, b);
        T *= vv.w;
    }
    stout(out, pid * 3 + 0, r, is32);
    stout(out, pid * 3 + 1, g, is32);
    stout(out, pid * 3 + 2, b, is32);
}

// -------------------------------- fallback: fused render over all gaussians
// (used only if ws_size can't hold the 2 MB segment buffer)
__global__ __launch_bounds__(256) void gs_render_all(
    const float* __restrict__ params_sorted,
    void* __restrict__ out,
    const void* __restrict__ intr)
{
    __shared__ float sp[SEG * 12];
    int t = threadIdx.x;
    int pid = blockIdx.x * 256 + t;
    bool is32 = detect32(intr);
    float pxf = (float)(pid & (WW - 1));
    float pyf = (float)(pid >> 7);

    float T = 1.0f, r = 0.f, g = 0.f, b = 0.f;
    for (int seg = 0; seg < NSEG; ++seg) {
        __syncthreads();
        const float4* src = (const float4*)(params_sorted + seg * SEG * 12);
        float4* dst = (float4*)sp;
        #pragma unroll
        for (int k = t; k < SEG * 3; k += 256) dst[k] = src[k];
        __syncthreads();
        for (int i = 0; i < SEG; ++i) {
            const float* gp = sp + i * 12;
            float dx = pxf - gp[0];
            float dy = pyf - gp[1];
            float pwr = -0.5f * (gp[2] * dx * dx + gp[4] * dy * dy) - gp[3] * dx * dy;
            pwr = fminf(pwr, 0.0f);
            float alpha = fminf(fmaxf(gp[5] * __expf(pwr), 0.0f), 0.99f);
            float wgt = alpha * T;
            r = fmaf(wgt, gp[6], r);
            g = fmaf(wgt, gp[7], g);
            b = fmaf(wgt, gp[8], b);
            T *= (1.0f - alpha);
        }
    }
    stout(out, pid * 3 + 0, r, is32);
    stout(out, pid * 3 + 1, g, is32);
    stout(out, pid * 3 + 2, b, is32);
}

extern "C" void kernel_launch(void* const* d_in, const int* in_sizes, int n_in,
                              void* d_out, int out_size, void* d_ws, size_t ws_size,
                              hipStream_t stream)
{
    const void* means      = d_in[0];
    const void* log_scales = d_in[1];
    const void* rotations  = d_in[2];
    const void* colors     = d_in[3];
    const void* opacities  = d_in[4];
    const void* intrinsics = d_in[5];
    const void* cam2world  = d_in[6];

    int n = in_sizes[4];
    if (n > NMAX) n = NMAX;

    // workspace layout
    size_t off_keys   = 0;                       // 16 KB
    size_t off_params = NMAX * 8;                // 96 KB
    size_t off_sorted = off_params + NMAX * 48;  // 96 KB
    size_t off_seg    = off_sorted + NMAX * 48;  // 2 MB
    size_t need_seg   = off_seg + (size_t)NSEG * HH * WW * 16;

    unsigned long long* keys = (unsigned long long*)((char*)d_ws + off_keys);
    float* params  = (float*)((char*)d_ws + off_params);
    float* sortedp = (float*)((char*)d_ws + off_sorted);
    float4* segbuf = (float4*)((char*)d_ws + off_seg);

    gs_preprocess<<<NMAX / 256, 256, 0, stream>>>(
        means, log_scales, rotations, colors, opacities, intrinsics, cam2world,
        n, keys, params);
    gs_rank_scatter<<<NMAX / 256, 256, 0, stream>>>(keys, params, sortedp, n);

    if (ws_size >= need_seg) {
        dim3 rg(HH * WW / 256, NSEG);
        gs_render<<<rg, 256, 0, stream>>>(sortedp, segbuf);
        gs_combine<<<HH * WW / 256, 256, 0, stream>>>(segbuf, d_out, intrinsics);
    } else {
        gs_render_all<<<HH * WW / 256, 256, 0, stream>>>(sortedp, d_out, intrinsics);
    }
}

// Round 5
// 99.001 us; speedup vs baseline: 1.5212x; 1.3003x over previous
//
#include <hip/hip_runtime.h>
#include <hip/hip_bf16.h>

#define NMAX 2048
#define HH 128
#define WW 128
#define NSEG 8
#define SEG 256            // NMAX / NSEG
#define NEARP 0.1f

// Runtime-adaptive input load: reference ships fp32; guard against a bf16
// dataset variant. Detected from intrinsics[0] (==150.0 iff fp32; bf16-packed
// bytes read as float give a denormal ~2e-41).
static __device__ __forceinline__ float ldin(const void* p, int i, bool is32) {
    return is32 ? ((const float*)p)[i]
                : __bfloat162float(((const __hip_bfloat16*)p)[i]);
}
static __device__ __forceinline__ bool detect32(const void* intr) {
    return ((const float*)intr)[0] > 1.0f;
}
static __device__ __forceinline__ void stout(void* out, int i, float v, bool is32) {
    if (is32) ((float*)out)[i] = v;
    else      ((__hip_bfloat16*)out)[i] = __float2bfloat16(v);
}

// Record layout (12 floats, 3x float4):
// [0]=u [1]=v [2]=na(=-0.5*cA) [3]=nb(=-cB) [4]=nc(=-0.5*cC) [5]=op
// [6]=cr [7]=cg [8]=cb [9..11] pad
// pwr = na*dx^2 + nb*dx*dy + nc*dy^2   (exact same value as reference form)

// ---------------------------------------------------------------- preprocess
__global__ __launch_bounds__(256) void gs_preprocess(
    const void* __restrict__ means,
    const void* __restrict__ log_scales,
    const void* __restrict__ rots,
    const void* __restrict__ colors,
    const void* __restrict__ opac,
    const void* __restrict__ intr,
    const void* __restrict__ c2w,
    int n,
    unsigned long long* __restrict__ keys,
    float* __restrict__ params)
{
    int i = blockIdx.x * blockDim.x + threadIdx.x;
    if (i >= NMAX) return;
    bool is32 = detect32(intr);
    if (i >= n) {
        // unique key (sorts to the end, stable by index)
        keys[i] = (((unsigned long long)0x7f800000u) << 32) | (unsigned int)i;
        return;
    }

    // camera: Rwc = Rcw^T, twc = -Rwc @ tcw
    float Rwc[3][3], twc[3];
    {
        float Rcw[3][3], tcw[3];
        for (int r = 0; r < 3; ++r) {
            for (int c = 0; c < 3; ++c) Rcw[r][c] = ldin(c2w, r * 4 + c, is32);
            tcw[r] = ldin(c2w, r * 4 + 3, is32);
        }
        for (int r = 0; r < 3; ++r)
            for (int c = 0; c < 3; ++c) Rwc[r][c] = Rcw[c][r];
        for (int r = 0; r < 3; ++r)
            twc[r] = -(Rwc[r][0] * tcw[0] + Rwc[r][1] * tcw[1] + Rwc[r][2] * tcw[2]);
    }
    float fx = ldin(intr, 0, is32), fy = ldin(intr, 4, is32);
    float cx = ldin(intr, 2, is32), cy = ldin(intr, 5, is32);

    float mx = ldin(means, 3 * i, is32), my = ldin(means, 3 * i + 1, is32),
          mz = ldin(means, 3 * i + 2, is32);
    float px = Rwc[0][0] * mx + Rwc[0][1] * my + Rwc[0][2] * mz + twc[0];
    float py = Rwc[1][0] * mx + Rwc[1][1] * my + Rwc[1][2] * mz + twc[1];
    float pz = Rwc[2][0] * mx + Rwc[2][1] * my + Rwc[2][2] * mz + twc[2];
    bool valid = pz > NEARP;
    float zc = fmaxf(pz, NEARP);
    float izc = 1.0f / zc;
    float u = fx * px * izc + cx;
    float v = fy * py * izc + cy;

    // quaternion -> R
    float qw = ldin(rots, 4 * i, is32), qx = ldin(rots, 4 * i + 1, is32),
          qy = ldin(rots, 4 * i + 2, is32), qz = ldin(rots, 4 * i + 3, is32);
    float nrm = sqrtf(qw * qw + qx * qx + qy * qy + qz * qz);
    float inv = 1.0f / fmaxf(nrm, 1e-8f);
    qw *= inv; qx *= inv; qy *= inv; qz *= inv;
    float xx = qx * qx, yy = qy * qy, zz = qz * qz;
    float xy = qx * qy, xz = qx * qz, yz = qy * qz;
    float wx = qw * qx, wy = qw * qy, wz = qw * qz;
    float R[3][3] = {
        {1.f - 2.f * (yy + zz), 2.f * (xy - wz),       2.f * (xz + wy)},
        {2.f * (xy + wz),       1.f - 2.f * (xx + zz), 2.f * (yz - wx)},
        {2.f * (xz - wy),       2.f * (yz + wx),       1.f - 2.f * (xx + yy)}
    };
    float s2[3];
    for (int k = 0; k < 3; ++k) s2[k] = __expf(2.0f * ldin(log_scales, 3 * i + k, is32));

    // cov3d = R diag(s2) R^T + 1e-6 I
    float M[3][3];
    for (int r = 0; r < 3; ++r)
        for (int c = 0; c < 3; ++c)
            M[r][c] = R[r][0] * s2[0] * R[c][0] + R[r][1] * s2[1] * R[c][1]
                    + R[r][2] * s2[2] * R[c][2];
    M[0][0] += 1e-6f; M[1][1] += 1e-6f; M[2][2] += 1e-6f;

    // cov_cam = Rwc M Rwc^T
    float TM[3][3];
    for (int r = 0; r < 3; ++r)
        for (int c = 0; c < 3; ++c)
            TM[r][c] = Rwc[r][0] * M[0][c] + Rwc[r][1] * M[1][c] + Rwc[r][2] * M[2][c];
    float CC[3][3];
    for (int r = 0; r < 3; ++r)
        for (int c = 0; c < 3; ++c)
            CC[r][c] = TM[r][0] * Rwc[c][0] + TM[r][1] * Rwc[c][1] + TM[r][2] * Rwc[c][2];

    // J rows
    float J0[3] = {fx * izc, 0.0f, -fx * px * izc * izc};
    float J1[3] = {0.0f, fy * izc, -fy * py * izc * izc};
    float t0[3], t1[3];
    for (int c = 0; c < 3; ++c) {
        t0[c] = J0[0] * CC[0][c] + J0[1] * CC[1][c] + J0[2] * CC[2][c];
        t1[c] = J1[0] * CC[0][c] + J1[1] * CC[1][c] + J1[2] * CC[2][c];
    }
    float a  = t0[0] * J0[0] + t0[1] * J0[1] + t0[2] * J0[2] + 0.3f;
    float bq = t0[0] * J1[0] + t0[1] * J1[1] + t0[2] * J1[2];
    float cq = t1[0] * J1[0] + t1[1] * J1[1] + t1[2] * J1[2] + 0.3f;
    float det = fmaxf(a * cq - bq * bq, 1e-12f);
    float idet = 1.0f / det;
    float cA = cq * idet, cB = -bq * idet, cCc = a * idet;

    float o  = ldin(opac, i, is32);
    float op = valid ? (1.0f / (1.0f + __expf(-o))) : 0.0f;
    float cr = fminf(fmaxf(ldin(colors, 3 * i, is32), 0.f), 1.f);
    float cg = fminf(fmaxf(ldin(colors, 3 * i + 1, is32), 0.f), 1.f);
    float cb = fminf(fmaxf(ldin(colors, 3 * i + 2, is32), 0.f), 1.f);

    float zkey = valid ? zc : __builtin_inff();
    keys[i] = (((unsigned long long)__float_as_uint(zkey)) << 32) | (unsigned int)i;

    float* p = params + i * 12;
    p[0] = u;  p[1] = v;
    p[2] = -0.5f * cA;   // na
    p[3] = -cB;          // nb
    p[4] = -0.5f * cCc;  // nc
    p[5] = op;
    p[6] = cr; p[7] = cg; p[8] = cb; p[9] = 0.f; p[10] = 0.f; p[11] = 0.f;
}

// ------------------------------- rank-by-count (stable, unique keys) + scatter
// 64 blocks x 256 threads; block handles 32 gaussians, each split into 8
// interleaved key-chunks (j = c mod 8) so a wave reads 8 consecutive u64
// (conflict-free, 8-lane broadcast groups). One barrier pair; cooperative
// float4 scatter. Unique keys ((depth_bits<<32)|idx) => rank == stable argsort.
__global__ __launch_bounds__(256) void gs_rank_scatter(
    const unsigned long long* __restrict__ keys_in,
    const float* __restrict__ params_in,
    float* __restrict__ params_sorted,
    int n)
{
    __shared__ unsigned long long sk[NMAX];
    __shared__ int pr[32][9];   // +1 pad
    __shared__ int rk[32];
    int t = threadIdx.x;
    #pragma unroll
    for (int e = 0; e < 8; ++e) sk[t + e * 256] = keys_in[t + e * 256];
    __syncthreads();

    int g0 = blockIdx.x * 32;
    int gi = t >> 3;   // 0..31
    int c  = t & 7;    // chunk phase
    unsigned long long mykey = sk[g0 + gi];
    int cnt = 0;
    #pragma unroll 8
    for (int j = c; j < NMAX; j += 8)
        cnt += (sk[j] < mykey) ? 1 : 0;
    pr[gi][c] = cnt;
    __syncthreads();

    if (t < 32) {
        int r = 0;
        #pragma unroll
        for (int k = 0; k < 8; ++k) r += pr[t][k];
        rk[t] = r;
    }
    __syncthreads();

    if (t < 96) {
        int g = t / 3, q = t % 3;
        int src = g0 + g;
        float4 val;
        if (src < n) val = ((const float4*)params_in)[src * 3 + q];
        else         val = make_float4(0.f, 0.f, 0.f, 0.f);
        ((float4*)params_sorted)[rk[g] * 3 + q] = val;
    }
}

// ------------------------------------------- render (segmented, 2 px/thread)
__global__ __launch_bounds__(256) void gs_render(
    const float* __restrict__ params_sorted,
    float4* __restrict__ segbuf)
{
    __shared__ float sp[SEG * 12];
    int seg = blockIdx.y;
    int t = threadIdx.x;

    const float4* src = (const float4*)(params_sorted + seg * SEG * 12);
    float4* dst = (float4*)sp;
    #pragma unroll
    for (int k = t; k < SEG * 3; k += 256) dst[k] = src[k];
    __syncthreads();

    int pid0 = (blockIdx.x * 256 + t) * 2;       // adjacent-column pair
    float px0 = (float)(pid0 & (WW - 1));
    float px1 = px0 + 1.0f;
    float py  = (float)(pid0 >> 7);

    float T0 = 1.f, r0 = 0.f, g0 = 0.f, b0 = 0.f;
    float T1 = 1.f, r1 = 0.f, g1 = 0.f, b1 = 0.f;
    #pragma unroll 4
    for (int i = 0; i < SEG; ++i) {
        const float* gp = sp + i * 12;
        float4 A = *(const float4*)(gp);        // u v na nb
        float4 B = *(const float4*)(gp + 4);    // nc op cr cg
        float4 C = *(const float4*)(gp + 8);    // cb - - -
        float dy    = py - A.y;
        float nbdy  = A.w * dy;
        float ncdy2 = (B.x * dy) * dy;

        float dx0 = px0 - A.x;
        float p0 = fmaf(fmaf(A.z, dx0, nbdy), dx0, ncdy2);
        p0 = fminf(p0, 0.0f);
        float al0 = fminf(B.y * __expf(p0), 0.99f);
        float w0 = al0 * T0;
        r0 = fmaf(w0, B.z, r0);
        g0 = fmaf(w0, B.w, g0);
        b0 = fmaf(w0, C.x, b0);
        T0 *= (1.0f - al0);

        float dx1 = px1 - A.x;
        float p1 = fmaf(fmaf(A.z, dx1, nbdy), dx1, ncdy2);
        p1 = fminf(p1, 0.0f);
        float al1 = fminf(B.y * __expf(p1), 0.99f);
        float w1 = al1 * T1;
        r1 = fmaf(w1, B.z, r1);
        g1 = fmaf(w1, B.w, g1);
        b1 = fmaf(w1, C.x, b1);
        T1 *= (1.0f - al1);
    }
    segbuf[seg * (HH * WW) + pid0]     = make_float4(r0, g0, b0, T0);
    segbuf[seg * (HH * WW) + pid0 + 1] = make_float4(r1, g1, b1, T1);
}

// ---------------------------------------------------------------- combine
__global__ __launch_bounds__(256) void gs_combine(
    const float4* __restrict__ segbuf,
    void* __restrict__ out,
    const void* __restrict__ intr)
{
    int pid = blockIdx.x * 256 + threadIdx.x;
    if (pid >= HH * WW) return;
    bool is32 = detect32(intr);
    float r = 0.f, g = 0.f, b = 0.f, T = 1.0f;
    #pragma unroll
    for (int s = 0; s < NSEG; ++s) {
        float4 vv = segbuf[s * (HH * WW) + pid];
        r = fmaf(T, vv.x, r);
        g = fmaf(T, vv.y, g);
        b = fmaf(T, vv.z, b);
        T *= vv.w;
    }
    stout(out, pid * 3 + 0, r, is32);
    stout(out, pid * 3 + 1, g, is32);
    stout(out, pid * 3 + 2, b, is32);
}

// -------------------------------- fallback: fused render over all gaussians
// (used only if ws_size can't hold the 2 MB segment buffer)
__global__ __launch_bounds__(256) void gs_render_all(
    const float* __restrict__ params_sorted,
    void* __restrict__ out,
    const void* __restrict__ intr)
{
    __shared__ float sp[SEG * 12];
    int t = threadIdx.x;
    int pid = blockIdx.x * 256 + t;
    bool is32 = detect32(intr);
    float pxf = (float)(pid & (WW - 1));
    float pyf = (float)(pid >> 7);

    float T = 1.f, r = 0.f, g = 0.f, b = 0.f;
    for (int seg = 0; seg < NSEG; ++seg) {
        __syncthreads();
        const float4* src = (const float4*)(params_sorted + seg * SEG * 12);
        float4* dst = (float4*)sp;
        #pragma unroll
        for (int k = t; k < SEG * 3; k += 256) dst[k] = src[k];
        __syncthreads();
        for (int i = 0; i < SEG; ++i) {
            const float* gp = sp + i * 12;
            float dx = pxf - gp[0];
            float dy = pyf - gp[1];
            float pwr = fmaf(fmaf(gp[2], dx, gp[3] * dy), dx, (gp[4] * dy) * dy);
            pwr = fminf(pwr, 0.0f);
            float alpha = fminf(gp[5] * __expf(pwr), 0.99f);
            float wgt = alpha * T;
            r = fmaf(wgt, gp[6], r);
            g = fmaf(wgt, gp[7], g);
            b = fmaf(wgt, gp[8], b);
            T *= (1.0f - alpha);
        }
    }
    stout(out, pid * 3 + 0, r, is32);
    stout(out, pid * 3 + 1, g, is32);
    stout(out, pid * 3 + 2, b, is32);
}

extern "C" void kernel_launch(void* const* d_in, const int* in_sizes, int n_in,
                              void* d_out, int out_size, void* d_ws, size_t ws_size,
                              hipStream_t stream)
{
    const void* means      = d_in[0];
    const void* log_scales = d_in[1];
    const void* rotations  = d_in[2];
    const void* colors     = d_in[3];
    const void* opacities  = d_in[4];
    const void* intrinsics = d_in[5];
    const void* cam2world  = d_in[6];

    int n = in_sizes[4];
    if (n > NMAX) n = NMAX;

    // workspace layout
    size_t off_keys   = 0;                       // 16 KB
    size_t off_params = NMAX * 8;                // 96 KB
    size_t off_sorted = off_params + NMAX * 48;  // 96 KB
    size_t off_seg    = off_sorted + NMAX * 48;  // 2 MB
    size_t need_seg   = off_seg + (size_t)NSEG * HH * WW * 16;

    unsigned long long* keys = (unsigned long long*)((char*)d_ws + off_keys);
    float* params  = (float*)((char*)d_ws + off_params);
    float* sortedp = (float*)((char*)d_ws + off_sorted);
    float4* segbuf = (float4*)((char*)d_ws + off_seg);

    gs_preprocess<<<NMAX / 256, 256, 0, stream>>>(
        means, log_scales, rotations, colors, opacities, intrinsics, cam2world,
        n, keys, params);
    gs_rank_scatter<<<NMAX / 32, 256, 0, stream>>>(keys, params, sortedp, n);

    if (ws_size >= need_seg) {
        dim3 rg(HH * WW / 512, NSEG);   // 2 px/thread
        gs_render<<<rg, 256, 0, stream>>>(sortedp, segbuf);
        gs_combine<<<HH * WW / 256, 256, 0, stream>>>(segbuf, d_out, intrinsics);
    } else {
        gs_render_all<<<HH * WW / 256, 256, 0, stream>>>(sortedp, d_out, intrinsics);
    }
}